// Round 1
// baseline (654.049 us; speedup 1.0000x reference)
//
#include <hip/hip_runtime.h>
#include <math.h>

#define B_ 16
#define W_ 2048
#define C_ 512

// ---------------- workspace layout (floats) ----------------
// Xsp:    [B,W,C]      offset 0            (64 MB)
// indeg:  [B,C]        offset 16777216
// tt:     [B,W]        offset 16785408
// attnw:  [B,W,64]     offset 16818176
// sacon:  [B,W]        offset 18915328
#define OFF_XSP   0
#define OFF_INDEG (16777216)
#define OFF_TT    (16785408)
#define OFF_ATTNW (16818176)
#define OFF_SACON (18915328)

__device__ __forceinline__ float softplusf(float x) {
    return fmaxf(x, 0.f) + log1pf(expf(-fabsf(x)));
}

// ---- kernel 1: in-degree (column sums of relu(adj)) ----
// grid (B, C/256, 8), block 256. Split-K over i with atomics.
__global__ void indeg_kernel(const float* __restrict__ adj, float* __restrict__ indeg) {
    int b = blockIdx.x;
    int j = blockIdx.y * 256 + threadIdx.x;
    int i0 = blockIdx.z * 64;
    const float* base = adj + (size_t)b * C_ * C_ + (size_t)i0 * C_ + j;
    float s = 0.f;
#pragma unroll 8
    for (int i = 0; i < 64; i++) s += fmaxf(base[(size_t)i * C_], 0.f);
    atomicAdd(&indeg[b * C_ + j], s);
}

// ---- kernel 2: batched GEMM X_spatial = X_sfr @ relu(adj) / indeg ----
// grid (C/64, W/64, B), block 256 (16x16 threads, 4x4 microtile)
__global__ __launch_bounds__(256) void gemm_spatial(const float* __restrict__ X,
                                                    const float* __restrict__ adj,
                                                    const float* __restrict__ indeg,
                                                    float* __restrict__ Xsp) {
    __shared__ float As[64][68];
    __shared__ float Bs[64][68];
    const int b  = blockIdx.z;
    const int m0 = blockIdx.y * 64;
    const int n0 = blockIdx.x * 64;
    const float* Ab = X   + (size_t)b * W_ * C_ + (size_t)m0 * C_;
    const float* Bb = adj + (size_t)b * C_ * C_ + n0;

    const int tid = threadIdx.x;
    const int tx = tid & 15;   // output col group
    const int ty = tid >> 4;   // output row group
    const int lr = tid >> 4;   // load row
    const int lc = (tid & 15) * 4;

    float acc[4][4] = {};

    for (int k0 = 0; k0 < C_; k0 += 64) {
#pragma unroll
        for (int r = 0; r < 4; r++) {
            float4 v = *(const float4*)&Ab[(size_t)(lr + 16 * r) * C_ + k0 + lc];
            *(float4*)&As[lr + 16 * r][lc] = v;
        }
#pragma unroll
        for (int r = 0; r < 4; r++) {
            float4 v = *(const float4*)&Bb[(size_t)(k0 + lr + 16 * r) * C_ + lc];
            v.x = fmaxf(v.x, 0.f); v.y = fmaxf(v.y, 0.f);
            v.z = fmaxf(v.z, 0.f); v.w = fmaxf(v.w, 0.f);
            *(float4*)&Bs[lr + 16 * r][lc] = v;
        }
        __syncthreads();
#pragma unroll
        for (int kk = 0; kk < 64; kk++) {
            const float4 bv4 = *(const float4*)&Bs[kk][tx << 2];
            const float a0 = As[(ty << 2) + 0][kk];
            const float a1 = As[(ty << 2) + 1][kk];
            const float a2 = As[(ty << 2) + 2][kk];
            const float a3 = As[(ty << 2) + 3][kk];
            acc[0][0] = fmaf(a0, bv4.x, acc[0][0]);
            acc[0][1] = fmaf(a0, bv4.y, acc[0][1]);
            acc[0][2] = fmaf(a0, bv4.z, acc[0][2]);
            acc[0][3] = fmaf(a0, bv4.w, acc[0][3]);
            acc[1][0] = fmaf(a1, bv4.x, acc[1][0]);
            acc[1][1] = fmaf(a1, bv4.y, acc[1][1]);
            acc[1][2] = fmaf(a1, bv4.z, acc[1][2]);
            acc[1][3] = fmaf(a1, bv4.w, acc[1][3]);
            acc[2][0] = fmaf(a2, bv4.x, acc[2][0]);
            acc[2][1] = fmaf(a2, bv4.y, acc[2][1]);
            acc[2][2] = fmaf(a2, bv4.z, acc[2][2]);
            acc[2][3] = fmaf(a2, bv4.w, acc[2][3]);
            acc[3][0] = fmaf(a3, bv4.x, acc[3][0]);
            acc[3][1] = fmaf(a3, bv4.y, acc[3][1]);
            acc[3][2] = fmaf(a3, bv4.z, acc[3][2]);
            acc[3][3] = fmaf(a3, bv4.w, acc[3][3]);
        }
        __syncthreads();
    }

    // per-column scale = 1/max(indeg, 1e-4)
    const float* idg = indeg + b * C_ + n0 + (tx << 2);
    float4 scv;
    scv.x = 1.f / fmaxf(idg[0], 1e-4f);
    scv.y = 1.f / fmaxf(idg[1], 1e-4f);
    scv.z = 1.f / fmaxf(idg[2], 1e-4f);
    scv.w = 1.f / fmaxf(idg[3], 1e-4f);

#pragma unroll
    for (int i = 0; i < 4; i++) {
        float4 o;
        o.x = acc[i][0] * scv.x;
        o.y = acc[i][1] * scv.y;
        o.z = acc[i][2] * scv.z;
        o.w = acc[i][3] * scv.w;
        size_t row = (size_t)b * W_ + m0 + (ty << 2) + i;
        *(float4*)&Xsp[row * C_ + n0 + (tx << 2)] = o;
    }
}

// ---- kernel 3: temporal token (row means). wave per row. ----
__global__ void tt_kernel(const float* __restrict__ Xsp, float* __restrict__ tt) {
    int row = blockIdx.x * 4 + (threadIdx.x >> 6);
    int lane = threadIdx.x & 63;
    const float* p = Xsp + (size_t)row * C_;
    float s = 0.f;
#pragma unroll
    for (int c = 0; c < C_ / 64; c++) s += p[lane + c * 64];
#pragma unroll
    for (int off = 32; off > 0; off >>= 1) s += __shfl_down(s, off);
    if (lane == 0) tt[row] = s * (1.f / C_);
}

// ---- kernel 4: band-softmax attention weights (<=2*nside per row) ----
__global__ void attn_kernel(const float* __restrict__ tt,
                            const float* __restrict__ ltp,
                            const float* __restrict__ wqp, const float* __restrict__ bqp,
                            const float* __restrict__ wkp, const float* __restrict__ bkp,
                            const int* __restrict__ k1p, const int* __restrict__ k2p,
                            float* __restrict__ attnw, float* __restrict__ sacon) {
    int idx = blockIdx.x * 256 + threadIdx.x;
    if (idx >= B_ * W_) return;
    int b = idx / W_, i = idx % W_;
    const float temp = softplusf(ltp[0]) + 1e-4f;
    const float invt = 1.f / temp;
    const float wq = wqp[0], bq = bqp[0], wk = wkp[0], bk = bkp[0];
    const int K1 = k1p[0], K2 = k2p[0];
    int ns = K2 - K1 + 1;
    if (ns > 32) ns = 32;
    const int n2 = 2 * ns;
    const float q = wq * tt[idx] + bq;
    const float* ttb = tt + b * W_;

    // pass 1: max
    float mx = -INFINITY;
    for (int s = 0; s < n2; s++) {
        int j = (s < ns) ? (i - K2 + s) : (i + K1 + (s - ns));
        if (j >= 0 && j < W_) {
            float l = q * (wk * ttb[j] + bk) * invt;
            mx = fmaxf(mx, l);
        }
    }
    // pass 2: softmax denominator
    float T = 0.f;
    for (int s = 0; s < n2; s++) {
        int j = (s < ns) ? (i - K2 + s) : (i + K1 + (s - ns));
        if (j >= 0 && j < W_) {
            float l = q * (wk * ttb[j] + bk) * invt;
            T += expf(l - mx);
        }
    }
    // pass 3: S = sum of (p/T) in fp32, matching reference order of ops
    float S = 0.f;
    for (int s = 0; s < n2; s++) {
        int j = (s < ns) ? (i - K2 + s) : (i + K1 + (s - ns));
        if (j >= 0 && j < W_) {
            float l = q * (wk * ttb[j] + bk) * invt;
            S += expf(l - mx) / T;
        }
    }
    const float rn = 1.f / (S + 1e-6f);
    // pass 4: write weights
    float* wrow = attnw + (size_t)idx * 64;
    for (int s = 0; s < n2; s++) {
        int j = (s < ns) ? (i - K2 + s) : (i + K1 + (s - ns));
        float w = 0.f;
        if (j >= 0 && j < W_) {
            float l = q * (wk * ttb[j] + bk) * invt;
            w = (expf(l - mx) / T) * rn;
        }
        wrow[s] = w;
    }
    sacon[idx] = S * rn;
}

// ---- kernel 5: fused temporal aggregation + output epilogue ----
// block per (b,i) row; 256 threads x 2 columns
__global__ __launch_bounds__(256) void final_kernel(const float* __restrict__ Xsp,
                                                    const float* __restrict__ attnw,
                                                    const float* __restrict__ sacon,
                                                    const float* __restrict__ wvp, const float* __restrict__ bvp,
                                                    const float* __restrict__ wmup, const float* __restrict__ bmup,
                                                    const float* __restrict__ wsigp, const float* __restrict__ bsigp,
                                                    const int* __restrict__ k1p, const int* __restrict__ k2p,
                                                    float* __restrict__ out) {
    const int row = blockIdx.x;          // 0 .. B*W-1
    const int b = row / W_, i = row % W_;
    const int c0 = threadIdx.x;
    const int c1 = threadIdx.x + 256;
    const int K1 = k1p[0], K2 = k2p[0];
    int ns = K2 - K1 + 1;
    if (ns > 32) ns = 32;
    const int n2 = 2 * ns;
    const float* wrow = attnw + (size_t)row * 64;
    const float* Xb = Xsp + (size_t)b * W_ * C_;

    float a0 = 0.f, a1 = 0.f;
    for (int s = 0; s < n2; s++) {
        float w = wrow[s];
        int j = (s < ns) ? (i - K2 + s) : (i + K1 + (s - ns));
        j = min(max(j, 0), W_ - 1);
        const float* src = Xb + (size_t)j * C_;
        a0 = fmaf(w, src[c0], a0);
        a1 = fmaf(w, src[c1], a1);
    }
    const float S = sacon[row];
    const float wv = wvp[0], bv = bvp[0];
    const float wmu = wmup[0], bmu = bmup[0];
    const float wsig = wsigp[0], bsig = bsigp[0];

    const float xsp0 = Xsp[(size_t)row * C_ + c0];
    const float xsp1 = Xsp[(size_t)row * C_ + c1];
    const float xf0 = fmaf(wv, a0, bv * S) + xsp0;
    const float xf1 = fmaf(wv, a1, bv * S) + xsp1;

    const float mu0 = fminf(fmaxf(fmaf(wmu, xf0, bmu), -20.f), 20.f);
    const float mu1 = fminf(fmaxf(fmaf(wmu, xf1, bmu), -20.f), 20.f);
    const float sg0 = softplusf(fmaf(wsig, xf0, bsig)) + 0.1f;
    const float sg1 = softplusf(fmaf(wsig, xf1, bsig)) + 0.1f;

    const size_t N = (size_t)B_ * W_ * C_;
    const size_t base = (size_t)row * C_;
    out[base + c0] = mu0;
    out[base + c1] = mu1;
    out[N + base + c0] = sg0;
    out[N + base + c1] = sg1;
    out[2 * N + base + c0] = S;
    out[2 * N + base + c1] = S;
}

extern "C" void kernel_launch(void* const* d_in, const int* in_sizes, int n_in,
                              void* d_out, int out_size, void* d_ws, size_t ws_size,
                              hipStream_t stream) {
    const float* X_sfr = (const float*)d_in[0];
    const float* adj   = (const float*)d_in[1];
    const float* ltp   = (const float*)d_in[2];
    const float* wq    = (const float*)d_in[3];
    const float* bq    = (const float*)d_in[4];
    const float* wk    = (const float*)d_in[5];
    const float* bk    = (const float*)d_in[6];
    const float* wv    = (const float*)d_in[7];
    const float* bv    = (const float*)d_in[8];
    const float* wmu   = (const float*)d_in[9];
    const float* bmu   = (const float*)d_in[10];
    const float* wsig  = (const float*)d_in[11];
    const float* bsig  = (const float*)d_in[12];
    const int*   k1p   = (const int*)d_in[13];
    const int*   k2p   = (const int*)d_in[14];

    float* ws    = (float*)d_ws;
    float* Xsp   = ws + OFF_XSP;
    float* indeg = ws + OFF_INDEG;
    float* tt    = ws + OFF_TT;
    float* attnw = ws + OFF_ATTNW;
    float* sacon = ws + OFF_SACON;
    float* out   = (float*)d_out;

    hipMemsetAsync(indeg, 0, B_ * C_ * sizeof(float), stream);

    indeg_kernel<<<dim3(B_, C_ / 256, 8), 256, 0, stream>>>(adj, indeg);

    gemm_spatial<<<dim3(C_ / 64, W_ / 64, B_), 256, 0, stream>>>(X_sfr, adj, indeg, Xsp);

    tt_kernel<<<(B_ * W_) / 4, 256, 0, stream>>>(Xsp, tt);

    attn_kernel<<<(B_ * W_ + 255) / 256, 256, 0, stream>>>(tt, ltp, wq, bq, wk, bk,
                                                           k1p, k2p, attnw, sacon);

    final_kernel<<<B_ * W_, 256, 0, stream>>>(Xsp, attnw, sacon, wv, bv, wmu, bmu,
                                              wsig, bsig, k1p, k2p, out);
}

// Round 2
// 419.195 us; speedup vs baseline: 1.5602x; 1.5602x over previous
//
#include <hip/hip_runtime.h>
#include <math.h>

#define B_ 16
#define W_ 2048
#define C_ 512

// ---------------- workspace layout (bytes) ----------------
// Xb  (bf16) [B,W,C]  @ 0          (33554432 B)
// Bt  (bf16) [B,C,C]  @ 33554432   ( 8388608 B)   Bt[b][j][i] = relu(adj[b][i][j])/indeg[b][j]
// Xsp (bf16) [B,W,C]  @ 41943040   (33554432 B)
// indeg f32  [B,C]    @ 75497472   (   32768 B)
// tt    f32  [B,W]    @ 75530240   (  131072 B)
#define OFF_XB    0
#define OFF_BT    33554432
#define OFF_XSP   41943040
#define OFF_INDEG 75497472
#define OFF_TT    75530240

typedef short v8s __attribute__((ext_vector_type(8)));
typedef float v4f __attribute__((ext_vector_type(4)));

__device__ __forceinline__ float softplusf(float x) {
    return fmaxf(x, 0.f) + log1pf(expf(-fabsf(x)));
}
__device__ __forceinline__ unsigned short f2bf(float x) {
    unsigned int u = __float_as_uint(x);
    unsigned int r = (u + 0x7FFFu + ((u >> 16) & 1u)) >> 16;   // RNE
    return (unsigned short)r;
}
__device__ __forceinline__ float bf2f(unsigned int h) {
    return __uint_as_float(h << 16);
}

// ---- kernel 1: in-degree (column sums of relu(adj)) ----
__global__ void indeg_kernel(const float* __restrict__ adj, float* __restrict__ indeg) {
    int b = blockIdx.x;
    int j = blockIdx.y * 256 + threadIdx.x;
    int i0 = blockIdx.z * 64;
    const float* base = adj + (size_t)b * C_ * C_ + (size_t)i0 * C_ + j;
    float s = 0.f;
#pragma unroll 8
    for (int i = 0; i < 64; i++) s += fmaxf(base[(size_t)i * C_], 0.f);
    atomicAdd(&indeg[b * C_ + j], s);
}

// ---- kernel 2: X_sfr fp32 -> bf16 ----
__global__ void convertA(const float* __restrict__ X, ushort* __restrict__ Xb) {
    int idx = blockIdx.x * 256 + threadIdx.x;      // 4 elems per thread
    float4 v = ((const float4*)X)[idx];
    ushort4 o;
    o.x = f2bf(v.x); o.y = f2bf(v.y); o.z = f2bf(v.z); o.w = f2bf(v.w);
    ((ushort4*)Xb)[idx] = o;
}

// ---- kernel 3: adj -> relu/normalize/transpose bf16 : Bt[b][j][i] ----
__global__ void convertB(const float* __restrict__ adj, const float* __restrict__ indeg,
                         ushort* __restrict__ Bt) {
    __shared__ float t[32][33];
    int b = blockIdx.z, i0 = blockIdx.x * 32, j0 = blockIdx.y * 32;
    int tx = threadIdx.x & 31;
    int ty = threadIdx.x >> 5;            // 0..7
    const float* src = adj + (size_t)b * C_ * C_;
#pragma unroll
    for (int rr = 0; rr < 4; rr++) {
        int ii = ty + rr * 8;
        t[ii][tx] = fmaxf(src[(size_t)(i0 + ii) * C_ + j0 + tx], 0.f);
    }
    __syncthreads();
    int jr0 = threadIdx.x >> 4;           // 0..15
    int ic  = (threadIdx.x & 15) * 2;
#pragma unroll
    for (int pp = 0; pp < 2; pp++) {
        int jr = jr0 + pp * 16;
        float inv = 1.f / fmaxf(indeg[b * C_ + j0 + jr], 1e-4f);
        ushort2 o;
        o.x = f2bf(t[ic][jr] * inv);
        o.y = f2bf(t[ic + 1][jr] * inv);
        *(ushort2*)&Bt[(size_t)b * C_ * C_ + (size_t)(j0 + jr) * C_ + i0 + ic] = o;
    }
}

// ---- kernel 4: MFMA GEMM  Xsp[b] = Xb[b] (W x C) @ Bt[b]^T (C x C), bf16 out ----
// grid (C/128, W/128, B), 256 threads = 4 waves, 64x64 per wave, BK=32
#define LDA 56   // padded LDS stride in bf16 elems (112 B, 16B-aligned, 2-way banks)
__global__ __launch_bounds__(256) void gemm_mfma(const ushort* __restrict__ Xb,
                                                 const ushort* __restrict__ Bt,
                                                 ushort* __restrict__ Xsp) {
    __shared__ ushort As[128 * LDA];
    __shared__ ushort Bs[128 * LDA];
    const int b  = blockIdx.z;
    const int m0 = blockIdx.y * 128;
    const int n0 = blockIdx.x * 128;
    const int tid  = threadIdx.x;
    const int wave = tid >> 6, lane = tid & 63;
    const int quad = lane >> 4, l16 = lane & 15;
    const int mw = (wave & 1) * 64, nw = (wave >> 1) * 64;

    const ushort* Ag = Xb + (size_t)b * W_ * C_ + (size_t)m0 * C_;
    const ushort* Bg = Bt + (size_t)b * C_ * C_ + (size_t)n0 * C_;

    const int sm = tid >> 2;          // staging row 0..63 (and +64)
    const int sk = (tid & 3) * 8;     // staging k-chunk

    v4f acc[4][4];
#pragma unroll
    for (int mt = 0; mt < 4; mt++)
#pragma unroll
        for (int nt = 0; nt < 4; nt++)
            acc[mt][nt] = (v4f){0.f, 0.f, 0.f, 0.f};

    for (int k0 = 0; k0 < C_; k0 += 32) {
        uint4 a0 = *(const uint4*)(Ag + (size_t)sm * C_ + k0 + sk);
        uint4 a1 = *(const uint4*)(Ag + (size_t)(sm + 64) * C_ + k0 + sk);
        uint4 b0 = *(const uint4*)(Bg + (size_t)sm * C_ + k0 + sk);
        uint4 b1 = *(const uint4*)(Bg + (size_t)(sm + 64) * C_ + k0 + sk);
        __syncthreads();
        *(uint4*)&As[sm * LDA + sk]        = a0;
        *(uint4*)&As[(sm + 64) * LDA + sk] = a1;
        *(uint4*)&Bs[sm * LDA + sk]        = b0;
        *(uint4*)&Bs[(sm + 64) * LDA + sk] = b1;
        __syncthreads();

        v8s af[4], bf[4];
#pragma unroll
        for (int mt = 0; mt < 4; mt++)
            af[mt] = *(const v8s*)&As[(mw + mt * 16 + l16) * LDA + quad * 8];
#pragma unroll
        for (int nt = 0; nt < 4; nt++)
            bf[nt] = *(const v8s*)&Bs[(nw + nt * 16 + l16) * LDA + quad * 8];
#pragma unroll
        for (int mt = 0; mt < 4; mt++)
#pragma unroll
            for (int nt = 0; nt < 4; nt++)
                acc[mt][nt] = __builtin_amdgcn_mfma_f32_16x16x32_bf16(af[mt], bf[nt], acc[mt][nt], 0, 0, 0);
    }

    // epilogue: C/D layout col=lane&15, row=quad*4+reg
#pragma unroll
    for (int mt = 0; mt < 4; mt++) {
#pragma unroll
        for (int nt = 0; nt < 4; nt++) {
            int col = n0 + nw + nt * 16 + l16;
#pragma unroll
            for (int r = 0; r < 4; r++) {
                int row = m0 + mw + mt * 16 + quad * 4 + r;
                Xsp[((size_t)b * W_ + row) * C_ + col] = f2bf(acc[mt][nt][r]);
            }
        }
    }
}

// ---- kernel 5: temporal token (row means of bf16 Xsp) ----
__global__ void tt_kernel(const ushort* __restrict__ Xsp, float* __restrict__ tt) {
    int row  = blockIdx.x * 4 + (threadIdx.x >> 6);
    int lane = threadIdx.x & 63;
    uint4 v = *(const uint4*)(Xsp + (size_t)row * C_ + lane * 8);
    float s = bf2f(v.x & 0xffff) + bf2f(v.x >> 16)
            + bf2f(v.y & 0xffff) + bf2f(v.y >> 16)
            + bf2f(v.z & 0xffff) + bf2f(v.z >> 16)
            + bf2f(v.w & 0xffff) + bf2f(v.w >> 16);
#pragma unroll
    for (int off = 32; off > 0; off >>= 1) s += __shfl_xor(s, off);
    if (lane == 0) tt[row] = s * (1.f / C_);
}

// ---- kernel 6: fused band-softmax + temporal aggregation + epilogue ----
// one block per (b,i) row; wave-0 lanes 0..31 compute the <=22 softmax weights
__global__ __launch_bounds__(256) void final_kernel(const ushort* __restrict__ Xsp,
                                                    const float* __restrict__ tt,
                                                    const float* __restrict__ ltp,
                                                    const float* __restrict__ wqp, const float* __restrict__ bqp,
                                                    const float* __restrict__ wkp, const float* __restrict__ bkp,
                                                    const float* __restrict__ wvp, const float* __restrict__ bvp,
                                                    const float* __restrict__ wmup, const float* __restrict__ bmup,
                                                    const float* __restrict__ wsigp, const float* __restrict__ bsigp,
                                                    const int* __restrict__ k1p, const int* __restrict__ k2p,
                                                    float* __restrict__ out) {
    __shared__ float wlds[32];
    __shared__ float Slds;
    const int row = blockIdx.x;
    const int b = row >> 11, i = row & (W_ - 1);
    const int K1 = k1p[0], K2 = k2p[0];
    int ns = K2 - K1 + 1;
    if (ns > 16) ns = 16;
    const int n2 = 2 * ns;
    const int tid = threadIdx.x;

    if (tid < 32) {
        const float temp = softplusf(ltp[0]) + 1e-4f;
        const float invt = 1.f / temp;
        const float q = wqp[0] * tt[row] + bqp[0];
        const float wk = wkp[0], bk = bkp[0];
        const float* ttb = tt + b * W_;
        int s = tid;
        int j = (s < ns) ? (i - K2 + s) : (i + K1 + (s - ns));
        bool valid = (s < n2) && (j >= 0) && (j < W_);
        float l = valid ? (q * (wk * ttb[j] + bk) * invt) : -INFINITY;
        float mx = l;
#pragma unroll
        for (int off = 16; off > 0; off >>= 1) mx = fmaxf(mx, __shfl_xor(mx, off, 32));
        float e = valid ? expf(l - mx) : 0.f;
        float T = e;
#pragma unroll
        for (int off = 16; off > 0; off >>= 1) T += __shfl_xor(T, off, 32);
        float p = e / T;
        float S = p;
#pragma unroll
        for (int off = 16; off > 0; off >>= 1) S += __shfl_xor(S, off, 32);
        float rn = 1.f / (S + 1e-6f);
        wlds[tid] = p * rn;
        if (tid == 0) Slds = S * rn;
    }
    __syncthreads();

    const ushort* Xbp = Xsp + (size_t)b * W_ * C_;
    const int c2 = tid * 2;
    float a0 = 0.f, a1 = 0.f;
    for (int s = 0; s < n2; s++) {
        float w = wlds[s];
        int j = (s < ns) ? (i - K2 + s) : (i + K1 + (s - ns));
        j = min(max(j, 0), W_ - 1);
        unsigned int v = *(const unsigned int*)(Xbp + (size_t)j * C_ + c2);
        a0 = fmaf(w, bf2f(v & 0xffff), a0);
        a1 = fmaf(w, bf2f(v >> 16), a1);
    }
    const float S = Slds;
    const float wv = wvp[0], bv = bvp[0];
    const float wmu = wmup[0], bmu = bmup[0];
    const float wsig = wsigp[0], bsig = bsigp[0];

    unsigned int xv = *(const unsigned int*)(Xbp + (size_t)i * C_ + c2);
    const float xsp0 = bf2f(xv & 0xffff);
    const float xsp1 = bf2f(xv >> 16);
    const float xf0 = fmaf(wv, a0, bv * S) + xsp0;
    const float xf1 = fmaf(wv, a1, bv * S) + xsp1;

    float2 muv, sgv, scv;
    muv.x = fminf(fmaxf(fmaf(wmu, xf0, bmu), -20.f), 20.f);
    muv.y = fminf(fmaxf(fmaf(wmu, xf1, bmu), -20.f), 20.f);
    sgv.x = softplusf(fmaf(wsig, xf0, bsig)) + 0.1f;
    sgv.y = softplusf(fmaf(wsig, xf1, bsig)) + 0.1f;
    scv.x = S; scv.y = S;

    const size_t N = (size_t)B_ * W_ * C_;
    const size_t base = (size_t)row * C_ + c2;
    *(float2*)&out[base]         = muv;
    *(float2*)&out[N + base]     = sgv;
    *(float2*)&out[2 * N + base] = scv;
}

extern "C" void kernel_launch(void* const* d_in, const int* in_sizes, int n_in,
                              void* d_out, int out_size, void* d_ws, size_t ws_size,
                              hipStream_t stream) {
    const float* X_sfr = (const float*)d_in[0];
    const float* adj   = (const float*)d_in[1];
    const float* ltp   = (const float*)d_in[2];
    const float* wq    = (const float*)d_in[3];
    const float* bq    = (const float*)d_in[4];
    const float* wk    = (const float*)d_in[5];
    const float* bk    = (const float*)d_in[6];
    const float* wv    = (const float*)d_in[7];
    const float* bv    = (const float*)d_in[8];
    const float* wmu   = (const float*)d_in[9];
    const float* bmu   = (const float*)d_in[10];
    const float* wsig  = (const float*)d_in[11];
    const float* bsig  = (const float*)d_in[12];
    const int*   k1p   = (const int*)d_in[13];
    const int*   k2p   = (const int*)d_in[14];

    char* ws = (char*)d_ws;
    ushort* Xb    = (ushort*)(ws + OFF_XB);
    ushort* Bt    = (ushort*)(ws + OFF_BT);
    ushort* Xsp   = (ushort*)(ws + OFF_XSP);
    float*  indeg = (float*)(ws + OFF_INDEG);
    float*  tt    = (float*)(ws + OFF_TT);
    float*  out   = (float*)d_out;

    hipMemsetAsync(indeg, 0, B_ * C_ * sizeof(float), stream);

    indeg_kernel<<<dim3(B_, C_ / 256, 8), 256, 0, stream>>>(adj, indeg);

    convertA<<<(B_ * W_ * C_ / 4) / 256, 256, 0, stream>>>(X_sfr, Xb);

    convertB<<<dim3(C_ / 32, C_ / 32, B_), 256, 0, stream>>>(adj, indeg, Bt);

    gemm_mfma<<<dim3(C_ / 128, W_ / 128, B_), 256, 0, stream>>>(Xb, Bt, Xsp);

    tt_kernel<<<(B_ * W_) / 4, 256, 0, stream>>>(Xsp, tt);

    final_kernel<<<B_ * W_, 256, 0, stream>>>(Xsp, tt, ltp, wq, bq, wk, bk,
                                              wv, bv, wmu, bmu, wsig, bsig,
                                              k1p, k2p, out);
}

// Round 3
// 391.102 us; speedup vs baseline: 1.6723x; 1.0718x over previous
//
#include <hip/hip_runtime.h>
#include <math.h>

#define B_ 16
#define W_ 2048
#define C_ 512

// ---------------- workspace layout (bytes) ----------------
// Xb  (bf16) [B,W,C]  @ 0          (33554432 B)
// Bt  (bf16) [B,C,C]  @ 33554432   ( 8388608 B)   Bt[b][j][i] = relu(adj[b][i][j])/indeg[b][j]
// Xsp (bf16) [B,W,C]  @ 41943040   (33554432 B)
// indeg f32  [B,C]    @ 75497472   (   32768 B)
// tt    f32  [B,W]    @ 75530240   (  131072 B)   (raw row sums; 1/C folded at consumer)
#define OFF_XB    0
#define OFF_BT    33554432
#define OFF_XSP   41943040
#define OFF_INDEG 75497472
#define OFF_TT    75530240

typedef short v8s __attribute__((ext_vector_type(8)));
typedef float v4f __attribute__((ext_vector_type(4)));
typedef unsigned int u32;

__device__ __forceinline__ float softplusf(float x) {
    return fmaxf(x, 0.f) + log1pf(expf(-fabsf(x)));
}
__device__ __forceinline__ unsigned short f2bf(float x) {
    unsigned int u = __float_as_uint(x);
    unsigned int r = (u + 0x7FFFu + ((u >> 16) & 1u)) >> 16;   // RNE
    return (unsigned short)r;
}
__device__ __forceinline__ float bf2f(unsigned int h) {
    return __uint_as_float(h << 16);
}
// async global->LDS, 16B per lane; LDS dest must be wave-uniform base + lane*16
__device__ __forceinline__ void gload16(const ushort* g, ushort* l) {
    __builtin_amdgcn_global_load_lds(
        (const __attribute__((address_space(1))) u32*)(g),
        (__attribute__((address_space(3))) u32*)(l), 16, 0, 0);
}

// ---- kernel 1: in-degree (column sums of relu(adj)) ----
__global__ void indeg_kernel(const float* __restrict__ adj, float* __restrict__ indeg) {
    int b = blockIdx.x;
    int j = blockIdx.y * 256 + threadIdx.x;
    int i0 = blockIdx.z * 64;
    const float* base = adj + (size_t)b * C_ * C_ + (size_t)i0 * C_ + j;
    float s = 0.f;
#pragma unroll 8
    for (int i = 0; i < 64; i++) s += fmaxf(base[(size_t)i * C_], 0.f);
    atomicAdd(&indeg[b * C_ + j], s);
}

// ---- kernel 2: X_sfr fp32 -> bf16 ----
__global__ void convertA(const float* __restrict__ X, ushort* __restrict__ Xb) {
    int idx = blockIdx.x * 256 + threadIdx.x;      // 4 elems per thread
    float4 v = ((const float4*)X)[idx];
    ushort4 o;
    o.x = f2bf(v.x); o.y = f2bf(v.y); o.z = f2bf(v.z); o.w = f2bf(v.w);
    ((ushort4*)Xb)[idx] = o;
}

// ---- kernel 3: adj -> relu/normalize/transpose bf16 : Bt[b][j][i] ----
__global__ void convertB(const float* __restrict__ adj, const float* __restrict__ indeg,
                         ushort* __restrict__ Bt) {
    __shared__ float t[32][33];
    int b = blockIdx.z, i0 = blockIdx.x * 32, j0 = blockIdx.y * 32;
    int tx = threadIdx.x & 31;
    int ty = threadIdx.x >> 5;            // 0..7
    const float* src = adj + (size_t)b * C_ * C_;
#pragma unroll
    for (int rr = 0; rr < 4; rr++) {
        int ii = ty + rr * 8;
        t[ii][tx] = fmaxf(src[(size_t)(i0 + ii) * C_ + j0 + tx], 0.f);
    }
    __syncthreads();
    int jr0 = threadIdx.x >> 4;           // 0..15
    int ic  = (threadIdx.x & 15) * 2;
#pragma unroll
    for (int pp = 0; pp < 2; pp++) {
        int jr = jr0 + pp * 16;
        float inv = 1.f / fmaxf(indeg[b * C_ + j0 + jr], 1e-4f);
        ushort2 o;
        o.x = f2bf(t[ic][jr] * inv);
        o.y = f2bf(t[ic + 1][jr] * inv);
        *(ushort2*)&Bt[(size_t)b * C_ * C_ + (size_t)(j0 + jr) * C_ + i0 + ic] = o;
    }
}

// ---- kernel 4: MFMA GEMM (m97 structure) + fused tt row-sum epilogue ----
// grid (C/128, W/128, B), 256 threads = 4 waves, 64x64 per wave, BK=32
// LDS tiles unpadded 128x32 bf16 (global_load_lds requires contiguous layout)
__global__ __launch_bounds__(256) void gemm_mfma(const ushort* __restrict__ Xb,
                                                 const ushort* __restrict__ Bt,
                                                 ushort* __restrict__ Xsp,
                                                 float* __restrict__ tt) {
    __shared__ ushort As[128 * 32];
    __shared__ ushort Bs[128 * 32];
    const int b  = blockIdx.z;
    const int m0 = blockIdx.y * 128;
    const int n0 = blockIdx.x * 128;
    const int tid  = threadIdx.x;
    const int wave = tid >> 6, lane = tid & 63;
    const int quad = lane >> 4, l16 = lane & 15;
    const int mw = (wave & 1) * 64, nw = (wave >> 1) * 64;

    const ushort* Ag = Xb + (size_t)b * W_ * C_ + (size_t)m0 * C_;
    const ushort* Bg = Bt + (size_t)b * C_ * C_ + (size_t)n0 * C_;

    const int sm = tid >> 2;          // staging row 0..63 (and +64)
    const int sk = (tid & 3) * 8;     // staging k-chunk (8 bf16 = 16B)

    v4f acc[4][4];
#pragma unroll
    for (int mt = 0; mt < 4; mt++)
#pragma unroll
        for (int nt = 0; nt < 4; nt++)
            acc[mt][nt] = (v4f){0.f, 0.f, 0.f, 0.f};

    for (int k0 = 0; k0 < C_; k0 += 32) {
        __syncthreads();   // previous iter's ds_reads done before overwrite
        gload16(Ag + (size_t)sm * C_ + k0 + sk,        As + tid * 8);
        gload16(Ag + (size_t)(sm + 64) * C_ + k0 + sk, As + 2048 + tid * 8);
        gload16(Bg + (size_t)sm * C_ + k0 + sk,        Bs + tid * 8);
        gload16(Bg + (size_t)(sm + 64) * C_ + k0 + sk, Bs + 2048 + tid * 8);
        __syncthreads();   // drains vmcnt before barrier

        v8s af[4], bf[4];
#pragma unroll
        for (int mt = 0; mt < 4; mt++)
            af[mt] = *(const v8s*)&As[(mw + mt * 16 + l16) * 32 + quad * 8];
#pragma unroll
        for (int nt = 0; nt < 4; nt++)
            bf[nt] = *(const v8s*)&Bs[(nw + nt * 16 + l16) * 32 + quad * 8];
#pragma unroll
        for (int mt = 0; mt < 4; mt++)
#pragma unroll
            for (int nt = 0; nt < 4; nt++)
                acc[mt][nt] = __builtin_amdgcn_mfma_f32_16x16x32_bf16(af[mt], bf[nt], acc[mt][nt], 0, 0, 0);
    }

    // epilogue A: store Xsp bf16. C/D layout: col=l16, row=quad*4+reg
#pragma unroll
    for (int mt = 0; mt < 4; mt++) {
#pragma unroll
        for (int nt = 0; nt < 4; nt++) {
            int col = n0 + nw + nt * 16 + l16;
#pragma unroll
            for (int r = 0; r < 4; r++) {
                int row = m0 + mw + mt * 16 + quad * 4 + r;
                Xsp[((size_t)b * W_ + row) * C_ + col] = f2bf(acc[mt][nt][r]);
            }
        }
    }

    // epilogue B: partial row sums for temporal token (fp32, atomic)
#pragma unroll
    for (int mt = 0; mt < 4; mt++) {
#pragma unroll
        for (int r = 0; r < 4; r++) {
            float s = acc[mt][0][r] + acc[mt][1][r] + acc[mt][2][r] + acc[mt][3][r];
            s += __shfl_xor(s, 1);
            s += __shfl_xor(s, 2);
            s += __shfl_xor(s, 4);
            s += __shfl_xor(s, 8);
            if (l16 == 0) {
                int row = m0 + mw + mt * 16 + quad * 4 + r;
                atomicAdd(&tt[b * W_ + row], s);
            }
        }
    }
}

// ---- kernel 5: fused band-softmax + temporal aggregation + epilogue ----
// wave per row (4 rows/block); lanes 0..31 of each wave compute the <=22 weights
__global__ __launch_bounds__(256) void final_kernel(const ushort* __restrict__ Xsp,
                                                    const float* __restrict__ tt,
                                                    const float* __restrict__ ltp,
                                                    const float* __restrict__ wqp, const float* __restrict__ bqp,
                                                    const float* __restrict__ wkp, const float* __restrict__ bkp,
                                                    const float* __restrict__ wvp, const float* __restrict__ bvp,
                                                    const float* __restrict__ wmup, const float* __restrict__ bmup,
                                                    const float* __restrict__ wsigp, const float* __restrict__ bsigp,
                                                    const int* __restrict__ k1p, const int* __restrict__ k2p,
                                                    float* __restrict__ out) {
    __shared__ float wsh[4][32];
    __shared__ float Ssh[4];
    const int wid = threadIdx.x >> 6, lane = threadIdx.x & 63;
    const int row = blockIdx.x * 4 + wid;
    const int b = row >> 11, i = row & (W_ - 1);
    const int K1 = k1p[0], K2 = k2p[0];
    int ns = K2 - K1 + 1;
    if (ns > 16) ns = 16;
    const int n2 = 2 * ns;

    if (lane < 32) {
        const float cinv = 1.f / C_;               // tt holds raw row sums
        const float temp = softplusf(ltp[0]) + 1e-4f;
        const float invt = 1.f / temp;
        const float q = (wqp[0] * cinv) * tt[row] + bqp[0];
        const float wk = wkp[0] * cinv, bk = bkp[0];
        const float* ttb = tt + b * W_;
        int s = lane;
        int j = (s < ns) ? (i - K2 + s) : (i + K1 + (s - ns));
        bool valid = (s < n2) && (j >= 0) && (j < W_);
        float l = valid ? (q * (wk * ttb[j] + bk) * invt) : -INFINITY;
        float mx = l;
#pragma unroll
        for (int off = 16; off > 0; off >>= 1) mx = fmaxf(mx, __shfl_xor(mx, off, 32));
        float e = valid ? expf(l - mx) : 0.f;
        float T = e;
#pragma unroll
        for (int off = 16; off > 0; off >>= 1) T += __shfl_xor(T, off, 32);
        float p = e / T;
        float S = p;
#pragma unroll
        for (int off = 16; off > 0; off >>= 1) S += __shfl_xor(S, off, 32);
        float rn = 1.f / (S + 1e-6f);
        wsh[wid][lane] = p * rn;
        if (lane == 0) Ssh[wid] = S * rn;
    }
    __syncthreads();

    const ushort* Xbp = Xsp + (size_t)b * W_ * C_;
    const int c8 = lane * 8;
    float a[8] = {0.f, 0.f, 0.f, 0.f, 0.f, 0.f, 0.f, 0.f};
    for (int s = 0; s < n2; s++) {
        float w = wsh[wid][s];
        int j = (s < ns) ? (i - K2 + s) : (i + K1 + (s - ns));
        j = min(max(j, 0), W_ - 1);
        uint4 v = *(const uint4*)(Xbp + (size_t)j * C_ + c8);
        a[0] = fmaf(w, bf2f(v.x & 0xffff), a[0]);
        a[1] = fmaf(w, bf2f(v.x >> 16),    a[1]);
        a[2] = fmaf(w, bf2f(v.y & 0xffff), a[2]);
        a[3] = fmaf(w, bf2f(v.y >> 16),    a[3]);
        a[4] = fmaf(w, bf2f(v.z & 0xffff), a[4]);
        a[5] = fmaf(w, bf2f(v.z >> 16),    a[5]);
        a[6] = fmaf(w, bf2f(v.w & 0xffff), a[6]);
        a[7] = fmaf(w, bf2f(v.w >> 16),    a[7]);
    }
    const float S = Ssh[wid];
    const float wv = wvp[0], bv = bvp[0];
    const float wmu = wmup[0], bmu = bmup[0];
    const float wsig = wsigp[0], bsig = bsigp[0];

    uint4 xv = *(const uint4*)(Xbp + (size_t)i * C_ + c8);
    float xs[8];
    xs[0] = bf2f(xv.x & 0xffff); xs[1] = bf2f(xv.x >> 16);
    xs[2] = bf2f(xv.y & 0xffff); xs[3] = bf2f(xv.y >> 16);
    xs[4] = bf2f(xv.z & 0xffff); xs[5] = bf2f(xv.z >> 16);
    xs[6] = bf2f(xv.w & 0xffff); xs[7] = bf2f(xv.w >> 16);

    float mu[8], sg[8];
#pragma unroll
    for (int k = 0; k < 8; k++) {
        float xf = fmaf(wv, a[k], bv * S) + xs[k];
        mu[k] = fminf(fmaxf(fmaf(wmu, xf, bmu), -20.f), 20.f);
        sg[k] = softplusf(fmaf(wsig, xf, bsig)) + 0.1f;
    }

    const size_t N = (size_t)B_ * W_ * C_;
    const size_t base = (size_t)row * C_ + c8;
    *(float4*)&out[base]     = (float4){mu[0], mu[1], mu[2], mu[3]};
    *(float4*)&out[base + 4] = (float4){mu[4], mu[5], mu[6], mu[7]};
    *(float4*)&out[N + base]     = (float4){sg[0], sg[1], sg[2], sg[3]};
    *(float4*)&out[N + base + 4] = (float4){sg[4], sg[5], sg[6], sg[7]};
    *(float4*)&out[2 * N + base]     = (float4){S, S, S, S};
    *(float4*)&out[2 * N + base + 4] = (float4){S, S, S, S};
}

extern "C" void kernel_launch(void* const* d_in, const int* in_sizes, int n_in,
                              void* d_out, int out_size, void* d_ws, size_t ws_size,
                              hipStream_t stream) {
    const float* X_sfr = (const float*)d_in[0];
    const float* adj   = (const float*)d_in[1];
    const float* ltp   = (const float*)d_in[2];
    const float* wq    = (const float*)d_in[3];
    const float* bq    = (const float*)d_in[4];
    const float* wk    = (const float*)d_in[5];
    const float* bk    = (const float*)d_in[6];
    const float* wv    = (const float*)d_in[7];
    const float* bv    = (const float*)d_in[8];
    const float* wmu   = (const float*)d_in[9];
    const float* bmu   = (const float*)d_in[10];
    const float* wsig  = (const float*)d_in[11];
    const float* bsig  = (const float*)d_in[12];
    const int*   k1p   = (const int*)d_in[13];
    const int*   k2p   = (const int*)d_in[14];

    char* ws = (char*)d_ws;
    ushort* Xb    = (ushort*)(ws + OFF_XB);
    ushort* Bt    = (ushort*)(ws + OFF_BT);
    ushort* Xsp   = (ushort*)(ws + OFF_XSP);
    float*  indeg = (float*)(ws + OFF_INDEG);
    float*  tt    = (float*)(ws + OFF_TT);
    float*  out   = (float*)d_out;

    // zero indeg + tt (contiguous) in one fill
    hipMemsetAsync(indeg, 0, (B_ * C_ + B_ * W_) * sizeof(float), stream);

    indeg_kernel<<<dim3(B_, C_ / 256, 8), 256, 0, stream>>>(adj, indeg);

    convertA<<<(B_ * W_ * C_ / 4) / 256, 256, 0, stream>>>(X_sfr, Xb);

    convertB<<<dim3(C_ / 32, C_ / 32, B_), 256, 0, stream>>>(adj, indeg, Bt);

    gemm_mfma<<<dim3(C_ / 128, W_ / 128, B_), 256, 0, stream>>>(Xb, Bt, Xsp, tt);

    final_kernel<<<(B_ * W_) / 4, 256, 0, stream>>>(Xsp, tt, ltp, wq, bq, wk, bk,
                                                    wv, bv, wmu, bmu, wsig, bsig,
                                                    k1p, k2p, out);
}

// Round 4
// 383.779 us; speedup vs baseline: 1.7042x; 1.0191x over previous
//
#include <hip/hip_runtime.h>
#include <math.h>

#define B_ 16
#define W_ 2048
#define C_ 512

// ---------------- workspace layout (bytes) ----------------
// Xb  (bf16) [B,W,C]  @ 0          (33554432 B)
// Bt  (bf16) [B,C,C]  @ 33554432   ( 8388608 B)   Bt[b][j][i] = relu(adj[b][i][j])/indeg[b][j]
// Xsp (bf16) [B,W,C]  @ 41943040   (33554432 B)
// tt    f32  [B,W]    @ 75497472   (  131072 B)   (raw row sums; 1/C folded at consumer)
#define OFF_XB    0
#define OFF_BT    33554432
#define OFF_XSP   41943040
#define OFF_TT    75497472

typedef short v8s __attribute__((ext_vector_type(8)));
typedef float v4f __attribute__((ext_vector_type(4)));
typedef unsigned int u32;

__device__ __forceinline__ float softplusf(float x) {
    return fmaxf(x, 0.f) + log1pf(expf(-fabsf(x)));
}
__device__ __forceinline__ unsigned short f2bf(float x) {
    unsigned int u = __float_as_uint(x);
    unsigned int r = (u + 0x7FFFu + ((u >> 16) & 1u)) >> 16;   // RNE
    return (unsigned short)r;
}
__device__ __forceinline__ float bf2f(unsigned int h) {
    return __uint_as_float(h << 16);
}
// async global->LDS, 16B per lane; LDS dest must be wave-uniform base + lane*16
__device__ __forceinline__ void gload16(const ushort* g, ushort* l) {
    __builtin_amdgcn_global_load_lds(
        (const __attribute__((address_space(1))) u32*)(g),
        (__attribute__((address_space(3))) u32*)(l), 16, 0, 0);
}

// ---- kernel 1: fused in-degree + relu/normalize/transpose bf16 ----
// one block per (32-column stripe, batch). Phase 1: column sums from HBM.
// Phase 2: re-read stripe (L2-resident, 64 KB) via 32x32 LDS transpose tiles.
__global__ __launch_bounds__(256) void prep_adj(const float* __restrict__ adj,
                                                ushort* __restrict__ Bt) {
    __shared__ float cs[8][32];
    __shared__ float inv[32];
    __shared__ float t[32][33];
    const int b = blockIdx.y, j0 = blockIdx.x * 32;
    const int tx = threadIdx.x & 31, ty = threadIdx.x >> 5;   // ty 0..7
    const float* src = adj + (size_t)b * C_ * C_;

    float s = 0.f;
#pragma unroll 4
    for (int it = 0; it < C_ / 8; it++)
        s += fmaxf(src[(size_t)(it * 8 + ty) * C_ + j0 + tx], 0.f);
    cs[ty][tx] = s;
    __syncthreads();
    if (ty == 0) {
        float tot = cs[0][tx] + cs[1][tx] + cs[2][tx] + cs[3][tx]
                  + cs[4][tx] + cs[5][tx] + cs[6][tx] + cs[7][tx];
        inv[tx] = 1.f / fmaxf(tot, 1e-4f);
    }

    const int jr = threadIdx.x >> 4;          // 0..15
    const int ic = (threadIdx.x & 15) * 2;
    for (int i0t = 0; i0t < C_; i0t += 32) {
        __syncthreads();
#pragma unroll
        for (int rr = 0; rr < 4; rr++) {
            int ii = ty + rr * 8;
            t[ii][tx] = fmaxf(src[(size_t)(i0t + ii) * C_ + j0 + tx], 0.f);
        }
        __syncthreads();
#pragma unroll
        for (int pp = 0; pp < 2; pp++) {
            int j = jr + pp * 16;
            float iv = inv[j];
            ushort2 o;
            o.x = f2bf(t[ic][j] * iv);
            o.y = f2bf(t[ic + 1][j] * iv);
            *(ushort2*)&Bt[(size_t)b * C_ * C_ + (size_t)(j0 + j) * C_ + i0t + ic] = o;
        }
    }
}

// ---- kernel 2: X_sfr fp32 -> bf16 ----
__global__ void convertA(const float* __restrict__ X, ushort* __restrict__ Xb) {
    int idx = blockIdx.x * 256 + threadIdx.x;      // 4 elems per thread
    float4 v = ((const float4*)X)[idx];
    ushort4 o;
    o.x = f2bf(v.x); o.y = f2bf(v.y); o.z = f2bf(v.z); o.w = f2bf(v.w);
    ((ushort4*)Xb)[idx] = o;
}

// ---- kernel 3: MFMA GEMM (m97 structure) + fused tt row-sum epilogue ----
__global__ __launch_bounds__(256) void gemm_mfma(const ushort* __restrict__ Xb,
                                                 const ushort* __restrict__ Bt,
                                                 ushort* __restrict__ Xsp,
                                                 float* __restrict__ tt) {
    __shared__ ushort As[128 * 32];
    __shared__ ushort Bs[128 * 32];
    const int b  = blockIdx.z;
    const int m0 = blockIdx.y * 128;
    const int n0 = blockIdx.x * 128;
    const int tid  = threadIdx.x;
    const int wave = tid >> 6, lane = tid & 63;
    const int quad = lane >> 4, l16 = lane & 15;
    const int mw = (wave & 1) * 64, nw = (wave >> 1) * 64;

    const ushort* Ag = Xb + (size_t)b * W_ * C_ + (size_t)m0 * C_;
    const ushort* Bg = Bt + (size_t)b * C_ * C_ + (size_t)n0 * C_;

    const int sm = tid >> 2;
    const int sk = (tid & 3) * 8;

    v4f acc[4][4];
#pragma unroll
    for (int mt = 0; mt < 4; mt++)
#pragma unroll
        for (int nt = 0; nt < 4; nt++)
            acc[mt][nt] = (v4f){0.f, 0.f, 0.f, 0.f};

    for (int k0 = 0; k0 < C_; k0 += 32) {
        __syncthreads();
        gload16(Ag + (size_t)sm * C_ + k0 + sk,        As + tid * 8);
        gload16(Ag + (size_t)(sm + 64) * C_ + k0 + sk, As + 2048 + tid * 8);
        gload16(Bg + (size_t)sm * C_ + k0 + sk,        Bs + tid * 8);
        gload16(Bg + (size_t)(sm + 64) * C_ + k0 + sk, Bs + 2048 + tid * 8);
        __syncthreads();

        v8s af[4], bf[4];
#pragma unroll
        for (int mt = 0; mt < 4; mt++)
            af[mt] = *(const v8s*)&As[(mw + mt * 16 + l16) * 32 + quad * 8];
#pragma unroll
        for (int nt = 0; nt < 4; nt++)
            bf[nt] = *(const v8s*)&Bs[(nw + nt * 16 + l16) * 32 + quad * 8];
#pragma unroll
        for (int mt = 0; mt < 4; mt++)
#pragma unroll
            for (int nt = 0; nt < 4; nt++)
                acc[mt][nt] = __builtin_amdgcn_mfma_f32_16x16x32_bf16(af[mt], bf[nt], acc[mt][nt], 0, 0, 0);
    }

#pragma unroll
    for (int mt = 0; mt < 4; mt++) {
#pragma unroll
        for (int nt = 0; nt < 4; nt++) {
            int col = n0 + nw + nt * 16 + l16;
#pragma unroll
            for (int r = 0; r < 4; r++) {
                int row = m0 + mw + mt * 16 + quad * 4 + r;
                Xsp[((size_t)b * W_ + row) * C_ + col] = f2bf(acc[mt][nt][r]);
            }
        }
    }

#pragma unroll
    for (int mt = 0; mt < 4; mt++) {
#pragma unroll
        for (int r = 0; r < 4; r++) {
            float s = acc[mt][0][r] + acc[mt][1][r] + acc[mt][2][r] + acc[mt][3][r];
            s += __shfl_xor(s, 1);
            s += __shfl_xor(s, 2);
            s += __shfl_xor(s, 4);
            s += __shfl_xor(s, 8);
            if (l16 == 0) {
                int row = m0 + mw + mt * 16 + quad * 4 + r;
                atomicAdd(&tt[b * W_ + row], s);
            }
        }
    }
}

// ---- kernel 4: fused band-softmax + temporal aggregation + epilogue ----
// 4 rows per wave (16 rows/block): union of 4 rows' bands = 2*(ns+3) rows,
// each loaded once and FMA'd into 4 accumulators.
__global__ __launch_bounds__(256) void final_kernel(const ushort* __restrict__ Xsp,
                                                    const float* __restrict__ tt,
                                                    const float* __restrict__ ltp,
                                                    const float* __restrict__ wqp, const float* __restrict__ bqp,
                                                    const float* __restrict__ wkp, const float* __restrict__ bkp,
                                                    const float* __restrict__ wvp, const float* __restrict__ bvp,
                                                    const float* __restrict__ wmup, const float* __restrict__ bmup,
                                                    const float* __restrict__ wsigp, const float* __restrict__ bsigp,
                                                    const int* __restrict__ k1p, const int* __restrict__ k2p,
                                                    float* __restrict__ out) {
    __shared__ float wlds[4][4][40];   // [wave][row-in-wave][union slot]
    __shared__ float Ssh[4][4];
    const int wid = threadIdx.x >> 6, lane = threadIdx.x & 63;
    const int i0w = blockIdx.x * 16 + wid * 4;    // global row base of this wave
    const int b = i0w >> 11, ib = i0w & (W_ - 1);
    const int K1 = k1p[0], K2 = k2p[0];
    int ns = K2 - K1 + 1;
    if (ns > 16) ns = 16;
    const int n2 = 2 * ns;
    const int nsL = ns + 3;            // union segment length
    const int nu = 2 * nsL;

    for (int k = threadIdx.x; k < 4 * 4 * 40; k += 256) ((float*)wlds)[k] = 0.f;
    __syncthreads();

    if (lane < 32) {
        const float cinv = 1.f / C_;
        const float temp = softplusf(ltp[0]) + 1e-4f;
        const float invt = 1.f / temp;
        const float wkc = wkp[0] * cinv, bk = bkp[0];
        const float wqc = wqp[0] * cinv, bq = bqp[0];
        const float* ttb = tt + b * W_;
        for (int r = 0; r < 4; r++) {
            const int i = ib + r;
            const float q = wqc * ttb[i] + bq;
            int s = lane;
            int j = (s < ns) ? (i - K2 + s) : (i + K1 + (s - ns));
            bool valid = (s < n2) && (j >= 0) && (j < W_);
            float l = valid ? (q * (wkc * ttb[j] + bk) * invt) : -INFINITY;
            float mx = l;
#pragma unroll
            for (int off = 16; off > 0; off >>= 1) mx = fmaxf(mx, __shfl_xor(mx, off, 32));
            float e = valid ? expf(l - mx) : 0.f;
            float T = e;
#pragma unroll
            for (int off = 16; off > 0; off >>= 1) T += __shfl_xor(T, off, 32);
            float p = e / T;
            float S = p;
#pragma unroll
            for (int off = 16; off > 0; off >>= 1) S += __shfl_xor(S, off, 32);
            float rn = 1.f / (S + 1e-6f);
            if (s < n2) {
                int u = (s < ns) ? (r + s) : (nsL + r + (s - ns));
                wlds[wid][r][u] = p * rn;
            }
            if (lane == 0) Ssh[wid][r] = S * rn;
        }
    }
    __syncthreads();

    const ushort* Xbp = Xsp + (size_t)b * W_ * C_;
    const int c8 = lane * 8;
    float acc[4][8];
#pragma unroll
    for (int r = 0; r < 4; r++)
#pragma unroll
        for (int k = 0; k < 8; k++) acc[r][k] = 0.f;

    for (int u = 0; u < nu; u++) {
        int j = (u < nsL) ? (ib - K2 + u) : (ib + K1 + (u - nsL));
        j = min(max(j, 0), W_ - 1);
        uint4 v = *(const uint4*)(Xbp + (size_t)j * C_ + c8);
        float x[8];
        x[0] = bf2f(v.x & 0xffff); x[1] = bf2f(v.x >> 16);
        x[2] = bf2f(v.y & 0xffff); x[3] = bf2f(v.y >> 16);
        x[4] = bf2f(v.z & 0xffff); x[5] = bf2f(v.z >> 16);
        x[6] = bf2f(v.w & 0xffff); x[7] = bf2f(v.w >> 16);
#pragma unroll
        for (int r = 0; r < 4; r++) {
            float w = wlds[wid][r][u];
#pragma unroll
            for (int k = 0; k < 8; k++) acc[r][k] = fmaf(w, x[k], acc[r][k]);
        }
    }

    const float wv = wvp[0], bv = bvp[0];
    const float wmu = wmup[0], bmu = bmup[0];
    const float wsig = wsigp[0], bsig = bsigp[0];
    const size_t N = (size_t)B_ * W_ * C_;

#pragma unroll
    for (int r = 0; r < 4; r++) {
        const float S = Ssh[wid][r];
        uint4 xv = *(const uint4*)(Xbp + (size_t)(ib + r) * C_ + c8);
        float xs[8];
        xs[0] = bf2f(xv.x & 0xffff); xs[1] = bf2f(xv.x >> 16);
        xs[2] = bf2f(xv.y & 0xffff); xs[3] = bf2f(xv.y >> 16);
        xs[4] = bf2f(xv.z & 0xffff); xs[5] = bf2f(xv.z >> 16);
        xs[6] = bf2f(xv.w & 0xffff); xs[7] = bf2f(xv.w >> 16);

        float mu[8], sg[8];
#pragma unroll
        for (int k = 0; k < 8; k++) {
            float xf = fmaf(wv, acc[r][k], bv * S) + xs[k];
            mu[k] = fminf(fmaxf(fmaf(wmu, xf, bmu), -20.f), 20.f);
            sg[k] = softplusf(fmaf(wsig, xf, bsig)) + 0.1f;
        }

        const size_t base = (size_t)(i0w + r) * C_ + c8;
        *(float4*)&out[base]     = (float4){mu[0], mu[1], mu[2], mu[3]};
        *(float4*)&out[base + 4] = (float4){mu[4], mu[5], mu[6], mu[7]};
        *(float4*)&out[N + base]     = (float4){sg[0], sg[1], sg[2], sg[3]};
        *(float4*)&out[N + base + 4] = (float4){sg[4], sg[5], sg[6], sg[7]};
        *(float4*)&out[2 * N + base]     = (float4){S, S, S, S};
        *(float4*)&out[2 * N + base + 4] = (float4){S, S, S, S};
    }
}

extern "C" void kernel_launch(void* const* d_in, const int* in_sizes, int n_in,
                              void* d_out, int out_size, void* d_ws, size_t ws_size,
                              hipStream_t stream) {
    const float* X_sfr = (const float*)d_in[0];
    const float* adj   = (const float*)d_in[1];
    const float* ltp   = (const float*)d_in[2];
    const float* wq    = (const float*)d_in[3];
    const float* bq    = (const float*)d_in[4];
    const float* wk    = (const float*)d_in[5];
    const float* bk    = (const float*)d_in[6];
    const float* wv    = (const float*)d_in[7];
    const float* bv    = (const float*)d_in[8];
    const float* wmu   = (const float*)d_in[9];
    const float* bmu   = (const float*)d_in[10];
    const float* wsig  = (const float*)d_in[11];
    const float* bsig  = (const float*)d_in[12];
    const int*   k1p   = (const int*)d_in[13];
    const int*   k2p   = (const int*)d_in[14];

    char* ws = (char*)d_ws;
    ushort* Xb  = (ushort*)(ws + OFF_XB);
    ushort* Bt  = (ushort*)(ws + OFF_BT);
    ushort* Xsp = (ushort*)(ws + OFF_XSP);
    float*  tt  = (float*)(ws + OFF_TT);
    float*  out = (float*)d_out;

    hipMemsetAsync(tt, 0, B_ * W_ * sizeof(float), stream);

    prep_adj<<<dim3(C_ / 32, B_), 256, 0, stream>>>(adj, Bt);

    convertA<<<(B_ * W_ * C_ / 4) / 256, 256, 0, stream>>>(X_sfr, Xb);

    gemm_mfma<<<dim3(C_ / 128, W_ / 128, B_), 256, 0, stream>>>(Xb, Bt, Xsp, tt);

    final_kernel<<<(B_ * W_) / 16, 256, 0, stream>>>(Xsp, tt, ltp, wq, bq, wk, bk,
                                                     wv, bv, wmu, bmu, wsig, bsig,
                                                     k1p, k2p, out);
}